// Round 1
// baseline (2011.748 us; speedup 1.0000x reference)
//
#include <hip/hip_runtime.h>
#include <stdint.h>

#define BATCH 128
#define SEQ   256
#define NC    16
#define HID   256
#define G4    1024   // 4*HID

// ---------- helpers ----------
__device__ __forceinline__ uint32_t f2bfbits(float f){
  uint32_t u = __float_as_uint(f);
  u += 0x7fffu + ((u >> 16) & 1u);   // RNE to bf16
  return u >> 16;
}
__device__ __forceinline__ float bflo(uint32_t u){ return __uint_as_float(u << 16); }
__device__ __forceinline__ float bfhi(uint32_t u){ return __uint_as_float(u & 0xffff0000u); }
__device__ __forceinline__ float sigmoidf_(float x){ return 1.f / (1.f + expf(-x)); }

// ---------- pack weights: W [G][K] f32 -> Q uint4 rows, k-major ----------
// Q[(k/8)*G + g] holds bf16 of W[g][k..k+7]  (pairs packed lo/hi)
__global__ void pack_w(const float* __restrict__ W, uint4* __restrict__ Q, int G, int K){
  int idx = blockIdx.x * blockDim.x + threadIdx.x;
  int kq = K >> 3;
  if (idx >= G * kq) return;
  int kk = idx % kq;             // lanes consecutive in kk -> coalesced row reads
  int g  = idx / kq;
  const float* r = W + (size_t)g * K + (kk << 3);
  uint4 q;
  q.x = (f2bfbits(r[1]) << 16) | f2bfbits(r[0]);
  q.y = (f2bfbits(r[3]) << 16) | f2bfbits(r[2]);
  q.z = (f2bfbits(r[5]) << 16) | f2bfbits(r[4]);
  q.w = (f2bfbits(r[7]) << 16) | f2bfbits(r[6]);
  Q[(size_t)kk * G + g] = q;
}

// ---------- visit embedding: x[bs][h] = sum_nc emb[codes][h]*mask ----------
__global__ void gather_x(const int* __restrict__ codes, const float* __restrict__ mask,
                         const float* __restrict__ emb, uint16_t* __restrict__ xbf){
  int bs = blockIdx.x;
  int t  = threadIdx.x;            // 256 threads, one per h
  __shared__ int   scd[NC];
  __shared__ float smk[NC];
  if (t < NC){ scd[t] = codes[bs * NC + t]; smk[t] = mask[bs * NC + t]; }
  __syncthreads();
  float acc = 0.f;
  #pragma unroll
  for (int k = 0; k < NC; k++)
    acc += emb[(size_t)scd[k] * HID + t] * smk[k];
  xbf[(size_t)bs * HID + t] = (uint16_t)f2bfbits(acc);
}

// ---------- xp = x @ Uall_w^T + Uall_b : [32768,256]@[256,1024] ----------
template<bool XPF32>
__global__ __launch_bounds__(256) void xp_gemm(const uint16_t* __restrict__ xbf,
    const float* __restrict__ Uw, const float* __restrict__ Ub,
    float* __restrict__ xpf, uint16_t* __restrict__ xpb){
  __shared__ float As[64][33];
  __shared__ float Bs[64][33];
  int tid = threadIdx.x;
  int m0 = blockIdx.y * 64, n0 = blockIdx.x * 64;
  int ty = tid >> 4, tx = tid & 15;
  int lr = tid >> 2, lc = (tid & 3) * 8;
  float acc[4][4] = {};
  for (int k0 = 0; k0 < 256; k0 += 32){
    uint4 av = *(const uint4*)(xbf + (size_t)(m0 + lr) * 256 + k0 + lc);
    const float4* bp = (const float4*)(Uw + (size_t)(n0 + lr) * 256 + k0 + lc);
    float4 b0 = bp[0], b1 = bp[1];
    __syncthreads();
    As[lr][lc+0] = bflo(av.x); As[lr][lc+1] = bfhi(av.x);
    As[lr][lc+2] = bflo(av.y); As[lr][lc+3] = bfhi(av.y);
    As[lr][lc+4] = bflo(av.z); As[lr][lc+5] = bfhi(av.z);
    As[lr][lc+6] = bflo(av.w); As[lr][lc+7] = bfhi(av.w);
    Bs[lr][lc+0] = b0.x; Bs[lr][lc+1] = b0.y; Bs[lr][lc+2] = b0.z; Bs[lr][lc+3] = b0.w;
    Bs[lr][lc+4] = b1.x; Bs[lr][lc+5] = b1.y; Bs[lr][lc+6] = b1.z; Bs[lr][lc+7] = b1.w;
    __syncthreads();
    #pragma unroll
    for (int kk = 0; kk < 32; kk++){
      float a0 = As[ty*4+0][kk], a1 = As[ty*4+1][kk], a2 = As[ty*4+2][kk], a3 = As[ty*4+3][kk];
      float c0 = Bs[tx*4+0][kk], c1 = Bs[tx*4+1][kk], c2 = Bs[tx*4+2][kk], c3 = Bs[tx*4+3][kk];
      acc[0][0] += a0*c0; acc[0][1] += a0*c1; acc[0][2] += a0*c2; acc[0][3] += a0*c3;
      acc[1][0] += a1*c0; acc[1][1] += a1*c1; acc[1][2] += a1*c2; acc[1][3] += a1*c3;
      acc[2][0] += a2*c0; acc[2][1] += a2*c1; acc[2][2] += a2*c2; acc[2][3] += a2*c3;
      acc[3][0] += a3*c0; acc[3][1] += a3*c1; acc[3][2] += a3*c2; acc[3][3] += a3*c3;
    }
  }
  float bias[4];
  #pragma unroll
  for (int j = 0; j < 4; j++) bias[j] = Ub[n0 + tx*4 + j];
  #pragma unroll
  for (int i = 0; i < 4; i++){
    size_t row = (size_t)(m0 + ty*4 + i) * G4 + n0 + tx*4;
    #pragma unroll
    for (int j = 0; j < 4; j++){
      float v = acc[i][j] + bias[j];
      if (XPF32) xpf[row + j] = v;
      else       xpb[row + j] = (uint16_t)f2bfbits(v);
    }
  }
}

// ---------- recurrence: 1 block per batch row, 1024 threads ----------
template<bool XPF32>
__global__ __launch_bounds__(1024) void recurrence(
    const uint4* __restrict__ WallQ,   // [32][1024] k-major packed bf16 (8 k per uint4)
    const float* __restrict__ Wall_b,  // [1024]
    const uint4* __restrict__ WdQ,     // [32][256]
    const float* __restrict__ Wd_b,    // [256]
    const float* __restrict__ xpf, const uint16_t* __restrict__ xpb,
    const float* __restrict__ times,   // [128][256]
    float* __restrict__ out)           // [128][256][256]
{
  int b = blockIdx.x, g = threadIdx.x;
  __shared__ float sh[HID], sc_[HID], souts[G4];
  if (g < HID){ sh[g] = 0.f; sc_[g] = 0.f; }
  __syncthreads();
  const float wall_bias = Wall_b[g];
  const float wd_bias   = (g < HID) ? Wd_b[g] : 0.f;

  for (int s = 0; s < SEQ; s++){
    size_t xidx = (size_t)(b * SEQ + s) * G4 + g;
    float dot = wall_bias + (XPF32 ? xpf[xidx] : bflo((uint32_t)xpb[xidx] << 16) * 0.f + __uint_as_float(((uint32_t)xpb[xidx]) << 16));
    // Wall dot: 32 uint4 rows, 8 k each
    #pragma unroll 4
    for (int kk = 0; kk < 32; kk++){
      uint4 w = WallQ[(size_t)kk * G4 + g];
      int kb = kk << 3;
      dot += bflo(w.x)*sh[kb+0] + bfhi(w.x)*sh[kb+1]
           + bflo(w.y)*sh[kb+2] + bfhi(w.y)*sh[kb+3]
           + bflo(w.z)*sh[kb+4] + bfhi(w.z)*sh[kb+5]
           + bflo(w.w)*sh[kb+6] + bfhi(w.w)*sh[kb+7];
    }
    float wdot = 0.f;
    if (g < HID){
      #pragma unroll 4
      for (int kk = 0; kk < 32; kk++){
        uint4 w = WdQ[(size_t)kk * HID + g];
        int kb = kk << 3;
        wdot += bflo(w.x)*sc_[kb+0] + bfhi(w.x)*sc_[kb+1]
              + bflo(w.y)*sc_[kb+2] + bfhi(w.y)*sc_[kb+3]
              + bflo(w.z)*sc_[kb+4] + bfhi(w.z)*sc_[kb+5]
              + bflo(w.w)*sc_[kb+6] + bfhi(w.w)*sc_[kb+7];
      }
    }
    souts[g] = dot;
    __syncthreads();
    if (g < HID){
      float t_s = 1.f / logf(times[b * SEQ + s] + 2.7183f);
      float fg = sigmoidf_(souts[g]);
      float ig = sigmoidf_(souts[g +     HID]);
      float og = sigmoidf_(souts[g + 2 * HID]);
      float ct = sigmoidf_(souts[g + 3 * HID]);
      float cs1  = tanhf(wdot + wd_bias);
      float cold = sc_[g];
      float cadj = (cold - cs1) + cs1 * t_s;
      float cn = fg * cadj + ig * ct;
      float hn = og * tanhf(cn);
      out[((size_t)b * SEQ + s) * HID + g] = hn;
      sc_[g] = cn; sh[g] = hn;
    }
    __syncthreads();
  }
}

// ---------- host ----------
extern "C" void kernel_launch(void* const* d_in, const int* in_sizes, int n_in,
                              void* d_out, int out_size, void* d_ws, size_t ws_size,
                              hipStream_t stream){
  const int*   codes  = (const int*)  d_in[0];
  const float* mask   = (const float*)d_in[1];
  const float* times  = (const float*)d_in[2];
  const float* emb    = (const float*)d_in[3];
  const float* Wall_w = (const float*)d_in[4];
  const float* Wall_b = (const float*)d_in[5];
  const float* Uall_w = (const float*)d_in[6];
  const float* Uall_b = (const float*)d_in[7];
  const float* Wd_w   = (const float*)d_in[8];
  const float* Wd_b   = (const float*)d_in[9];
  float* out = (float*)d_out;

  char* ws = (char*)d_ws;
  const size_t offWall = 0;                       // 32*1024*16 = 524288
  const size_t offWd   = 524288;                  // 32*256*16  = 131072
  const size_t offX    = 655360;                  // 32768*256*2 = 16777216
  const size_t offXP   = 17432576;
  const size_t xpF32Bytes = (size_t)32768 * 1024 * 4;  // 134 MB
  bool xpf32 = (ws_size >= offXP + xpF32Bytes);

  uint4*    WallQ = (uint4*)   (ws + offWall);
  uint4*    WdQ   = (uint4*)   (ws + offWd);
  uint16_t* xbf   = (uint16_t*)(ws + offX);
  float*    xpf   = (float*)   (ws + offXP);
  uint16_t* xpb   = (uint16_t*)(ws + offXP);

  hipLaunchKernelGGL(pack_w, dim3(128), dim3(256), 0, stream, Wall_w, WallQ, G4, HID);
  hipLaunchKernelGGL(pack_w, dim3(32),  dim3(256), 0, stream, Wd_w,   WdQ,   HID, HID);
  hipLaunchKernelGGL(gather_x, dim3(BATCH * SEQ), dim3(256), 0, stream, codes, mask, emb, xbf);
  if (xpf32){
    hipLaunchKernelGGL((xp_gemm<true>),  dim3(16, 512), dim3(256), 0, stream, xbf, Uall_w, Uall_b, xpf, xpb);
    hipLaunchKernelGGL((recurrence<true>),  dim3(BATCH), dim3(1024), 0, stream,
                       WallQ, Wall_b, WdQ, Wd_b, xpf, xpb, times, out);
  } else {
    hipLaunchKernelGGL((xp_gemm<false>), dim3(16, 512), dim3(256), 0, stream, xbf, Uall_w, Uall_b, xpf, xpb);
    hipLaunchKernelGGL((recurrence<false>), dim3(BATCH), dim3(1024), 0, stream,
                       WallQ, Wall_b, WdQ, Wd_b, xpf, xpb, times, out);
  }
}

// Round 2
// 1982.999 us; speedup vs baseline: 1.0145x; 1.0145x over previous
//
#include <hip/hip_runtime.h>
#include <stdint.h>

#define BATCH 128
#define SEQ   256
#define NC    16
#define HID   256
#define G4    1024

typedef _Float16 f16x2 __attribute__((ext_vector_type(2)));

__device__ __forceinline__ float fdot2_(uint32_t w, uint32_t h, float acc){
#if __has_builtin(__builtin_amdgcn_fdot2)
  union U { uint32_t u; f16x2 v; };
  U a, b; a.u = w; b.u = h;
  return __builtin_amdgcn_fdot2(a.v, b.v, acc, false);
#else
  union U { uint32_t u; _Float16 h[2]; };
  U a, b; a.u = w; b.u = h;
  return acc + (float)a.h[0]*(float)b.h[0] + (float)a.h[1]*(float)b.h[1];
#endif
}
__device__ __forceinline__ uint16_t f32_to_f16u(float f){
  union { _Float16 h; uint16_t u; } c; c.h = (_Float16)f; return c.u;
}
__device__ __forceinline__ float f16u_to_f32(uint32_t u){
  union { uint16_t u; _Float16 h; } c; c.u = (uint16_t)u; return (float)c.h;
}
__device__ __forceinline__ uint32_t f16pair(float a, float b){
  return (uint32_t)f32_to_f16u(a) | ((uint32_t)f32_to_f16u(b) << 16);
}
__device__ __forceinline__ float tanh_(float x){
  x = fminf(fmaxf(x, -15.f), 15.f);
  float e = __expf(2.f * x);
  return (e - 1.f) / (e + 1.f);
}
__device__ __forceinline__ float sigm_(float x){ return 1.f / (1.f + __expf(-x)); }

// ---- pack Wall: wpk[p][j4][t] uint4; t: o=t&511, kh=t>>9; row r=(o>>7)*256+p*128+(o&127)
// pairs cover k = kh*128 + 8*j4 + {0..7}
__global__ void pack_wall(const float* __restrict__ W, uint4* __restrict__ wpk){
  int L = blockIdx.x * blockDim.x + threadIdx.x;      // 32768
  if (L >= 2*16*1024) return;
  int t = L & 1023, j4 = (L >> 10) & 15, p = L >> 14;
  int o = t & 511, kh = t >> 9;
  int r = ((o >> 7) << 8) + (p << 7) + (o & 127);
  int kb = kh * 128 + 8 * j4;
  const float* row = W + (size_t)r * 256 + kb;
  uint4 q;
  q.x = f16pair(row[0], row[1]);
  q.y = f16pair(row[2], row[3]);
  q.z = f16pair(row[4], row[5]);
  q.w = f16pair(row[6], row[7]);
  wpk[L] = q;
}
// ---- pack Wd: wdpk[p][i4][t]; row = p*128 + (t>>3); k = (t&7)*32 + 8*i4 + {0..7}
__global__ void pack_wd(const float* __restrict__ W, uint4* __restrict__ wdpk){
  int L = blockIdx.x * blockDim.x + threadIdx.x;      // 8192
  if (L >= 2*4*1024) return;
  int t = L & 1023, i4 = (L >> 10) & 3, p = L >> 12;
  int row = (p << 7) + (t >> 3);
  int kb = (t & 7) * 32 + 8 * i4;
  const float* r = W + (size_t)row * 256 + kb;
  uint4 q;
  q.x = f16pair(r[0], r[1]);
  q.y = f16pair(r[2], r[3]);
  q.z = f16pair(r[4], r[5]);
  q.w = f16pair(r[6], r[7]);
  wdpk[L] = q;
}

__global__ void ts_k(const float* __restrict__ times, float* __restrict__ ts_all){
  int i = blockIdx.x * blockDim.x + threadIdx.x;
  if (i < BATCH * SEQ) ts_all[i] = 1.f / logf(times[i] + 2.7183f);
}

__global__ void gather_x(const int* __restrict__ codes, const float* __restrict__ mask,
                         const float* __restrict__ emb, uint16_t* __restrict__ xh){
  int bs = blockIdx.x;
  int t  = threadIdx.x;
  __shared__ int   scd[NC];
  __shared__ float smk[NC];
  if (t < NC){ scd[t] = codes[bs * NC + t]; smk[t] = mask[bs * NC + t]; }
  __syncthreads();
  float acc = 0.f;
  #pragma unroll
  for (int k = 0; k < NC; k++)
    acc += emb[(size_t)scd[k] * HID + t] * smk[k];
  xh[(size_t)bs * HID + t] = f32_to_f16u(acc);
}

// ---- xp2[(B)*256 + s][512] f16, B = b + 128*p, o = q*128 + u
__global__ __launch_bounds__(256) void xp_gemm(const uint16_t* __restrict__ xh,
    const float* __restrict__ Uw, const float* __restrict__ Ub,
    uint16_t* __restrict__ xp2){
  __shared__ float As[64][33];
  __shared__ float Bs[64][33];
  int tid = threadIdx.x;
  int m0 = blockIdx.y * 64, n0 = blockIdx.x * 64;
  int ty = tid >> 4, tx = tid & 15;
  int lr = tid >> 2, lc = (tid & 3) * 8;
  float acc[4][4] = {};
  for (int k0 = 0; k0 < 256; k0 += 32){
    uint4 av = *(const uint4*)(xh + (size_t)(m0 + lr) * 256 + k0 + lc);
    const float4* bp = (const float4*)(Uw + (size_t)(n0 + lr) * 256 + k0 + lc);
    float4 b0 = bp[0], b1 = bp[1];
    __syncthreads();
    As[lr][lc+0] = f16u_to_f32(av.x & 0xffff); As[lr][lc+1] = f16u_to_f32(av.x >> 16);
    As[lr][lc+2] = f16u_to_f32(av.y & 0xffff); As[lr][lc+3] = f16u_to_f32(av.y >> 16);
    As[lr][lc+4] = f16u_to_f32(av.z & 0xffff); As[lr][lc+5] = f16u_to_f32(av.z >> 16);
    As[lr][lc+6] = f16u_to_f32(av.w & 0xffff); As[lr][lc+7] = f16u_to_f32(av.w >> 16);
    Bs[lr][lc+0] = b0.x; Bs[lr][lc+1] = b0.y; Bs[lr][lc+2] = b0.z; Bs[lr][lc+3] = b0.w;
    Bs[lr][lc+4] = b1.x; Bs[lr][lc+5] = b1.y; Bs[lr][lc+6] = b1.z; Bs[lr][lc+7] = b1.w;
    __syncthreads();
    #pragma unroll
    for (int kk = 0; kk < 32; kk++){
      float a0 = As[ty*4+0][kk], a1 = As[ty*4+1][kk], a2 = As[ty*4+2][kk], a3 = As[ty*4+3][kk];
      float c0 = Bs[tx*4+0][kk], c1 = Bs[tx*4+1][kk], c2 = Bs[tx*4+2][kk], c3 = Bs[tx*4+3][kk];
      acc[0][0] += a0*c0; acc[0][1] += a0*c1; acc[0][2] += a0*c2; acc[0][3] += a0*c3;
      acc[1][0] += a1*c0; acc[1][1] += a1*c1; acc[1][2] += a1*c2; acc[1][3] += a1*c3;
      acc[2][0] += a2*c0; acc[2][1] += a2*c1; acc[2][2] += a2*c2; acc[2][3] += a2*c3;
      acc[3][0] += a3*c0; acc[3][1] += a3*c1; acc[3][2] += a3*c2; acc[3][3] += a3*c3;
    }
  }
  float bias[4];
  #pragma unroll
  for (int j = 0; j < 4; j++) bias[j] = Ub[n0 + tx*4 + j];
  #pragma unroll
  for (int i = 0; i < 4; i++){
    int m = m0 + ty*4 + i;
    int bb = m >> 8, s = m & 255;
    #pragma unroll
    for (int j = 0; j < 4; j++){
      int rr = n0 + tx*4 + j;
      int q = rr >> 8, rem = rr & 255, pp = rem >> 7, u = rem & 127;
      int o = (q << 7) + u;
      int Bch = bb + (pp << 7);
      xp2[((size_t)(Bch * SEQ + s)) * 512 + o] = f32_to_f16u(acc[i][j] + bias[j]);
    }
  }
}

// ---- recurrence: 256 blocks (B = b + 128p), 1024 threads, weights in registers
__global__ __launch_bounds__(1024) void recurrence(
    const uint4* __restrict__ wpk, const uint4* __restrict__ wdpk,
    const float* __restrict__ Wall_b, const float* __restrict__ Wd_b,
    const uint16_t* __restrict__ xp2, const float* __restrict__ ts_all,
    uint32_t* __restrict__ flags, uint32_t* __restrict__ payc,
    float* __restrict__ out)
{
  const int B = blockIdx.x;
  const int b = B & 127, p = B >> 7;
  const int t = threadIdx.x;
  const int o = t & 511, kh = t >> 9;
  const int Bp = B ^ 128;

  __shared__ __align__(16) uint32_t h_pk[128];    // h[256] as f16 pairs
  __shared__ __align__(16) uint32_t c_pk[8][20];  // padded chunks (16 words used each)
  __shared__ float pl[2][512];
  __shared__ float wd_red[128];

  uint4 ww[16];
  #pragma unroll
  for (int j4 = 0; j4 < 16; j4++) ww[j4] = wpk[(p * 16 + j4) * 1024 + t];
  uint4 wdw[4];
  #pragma unroll
  for (int i4 = 0; i4 < 4; i4++) wdw[i4] = wdpk[(p * 4 + i4) * 1024 + t];

  const int r = ((o >> 7) << 8) + (p << 7) + (o & 127);
  const float biasW = (kh == 0) ? Wall_b[r] : 0.f;
  float biasD = 0.f, c_reg = 0.f;
  if (t < 128) biasD = Wd_b[(p << 7) + t];

  if (t < 128) h_pk[t] = 0u;
  if (t < 160) ((uint32_t*)c_pk)[t] = 0u;
  __syncthreads();

  const uint16_t* xp_my = xp2 + (size_t)B * SEQ * 512;
  float xcur = (kh == 0) ? f16u_to_f32(xp_my[o]) : 0.f;

  for (int s = 0; s < SEQ; s++){
    uint16_t xnraw = 0;
    if (kh == 0 && s + 1 < SEQ) xnraw = xp_my[(size_t)(s + 1) * 512 + o];

    // Wall matvec (f16 dot2)
    float d = (kh == 0) ? (biasW + xcur) : 0.f;
    const uint4* hp4 = (const uint4*)h_pk;
    #pragma unroll
    for (int j4 = 0; j4 < 16; j4++){
      uint4 hv = hp4[kh * 16 + j4];
      uint4 w = ww[j4];
      d = fdot2_(w.x, hv.x, d);
      d = fdot2_(w.y, hv.y, d);
      d = fdot2_(w.z, hv.z, d);
      d = fdot2_(w.w, hv.w, d);
    }
    pl[kh][o] = d;

    // Wd matvec
    const int ks = t & 7, row = t >> 3;
    float wdd = 0.f;
    {
      const uint4* cp4 = (const uint4*)&c_pk[ks][0];
      #pragma unroll
      for (int i4 = 0; i4 < 4; i4++){
        uint4 cv = cp4[i4];
        uint4 w = wdw[i4];
        wdd = fdot2_(w.x, cv.x, wdd);
        wdd = fdot2_(w.y, cv.y, wdd);
        wdd = fdot2_(w.z, cv.z, wdd);
        wdd = fdot2_(w.w, cv.w, wdd);
      }
    }
    wdd += __shfl_xor(wdd, 1);
    wdd += __shfl_xor(wdd, 2);
    wdd += __shfl_xor(wdd, 4);
    if (ks == 0) wd_red[row] = wdd;
    __syncthreads();                                   // B1

    if (t < 128){
      const int j = t;
      float pf = pl[0][j]       + pl[1][j];
      float pi = pl[0][128 + j] + pl[1][128 + j];
      float po = pl[0][256 + j] + pl[1][256 + j];
      float pc = pl[0][384 + j] + pl[1][384 + j];
      float tsv  = ts_all[b * SEQ + s];
      float wdot = wd_red[j] + biasD;
      float cs1  = tanh_(wdot);
      float cadj = (c_reg - cs1) + cs1 * tsv;
      float fg = sigm_(pf), ig = sigm_(pi), og = sigm_(po), ct = sigm_(pc);
      float cn = fg * cadj + ig * ct;
      float hn = og * tanh_(cn);
      c_reg = cn;
      union { float f; uint32_t u; } hu; hu.f = hn;
      __hip_atomic_store((uint32_t*)&out[((size_t)(b * SEQ + s)) * HID + (p << 7) + j], hu.u,
                         __ATOMIC_RELAXED, __HIP_MEMORY_SCOPE_AGENT);
      uint32_t h16 = f32_to_f16u(hn);
      uint32_t c16 = f32_to_f16u(cn);
      ((uint16_t*)h_pk)[(p << 7) + j] = (uint16_t)h16;
      int u = (p << 7) + j;
      ((uint16_t*)c_pk)[(((u >> 5) * 20 + ((u >> 1) & 15)) << 1) + (u & 1)] = (uint16_t)c16;
      uint32_t other = __shfl_xor(c16, 1);
      if ((j & 1) == 0 && s + 1 < SEQ){
        uint32_t pw = c16 | (other << 16);
        __hip_atomic_store(&payc[((size_t)(B * SEQ + s)) * 64 + (j >> 1)], pw,
                           __ATOMIC_RELAXED, __HIP_MEMORY_SCOPE_AGENT);
      }
    }
    if (kh == 0) xcur = f16u_to_f32(xnraw);
    __syncthreads();                                   // B2 (drains all stores: vmcnt(0))

    if (s + 1 < SEQ){
      if (t == 0){
        uint32_t tag = 0x5AB10000u + (uint32_t)s;
        __hip_atomic_store(&flags[B * SEQ + s], tag, __ATOMIC_RELEASE, __HIP_MEMORY_SCOPE_AGENT);
        while (__hip_atomic_load(&flags[Bp * SEQ + s], __ATOMIC_ACQUIRE, __HIP_MEMORY_SCOPE_AGENT) != tag)
          __builtin_amdgcn_s_sleep(1);
      }
      __syncthreads();                                 // B3
      if (t < 128){
        const int j = t;
        uint32_t hv = __hip_atomic_load((uint32_t*)&out[((size_t)(b * SEQ + s)) * HID + ((1 - p) << 7) + j],
                                        __ATOMIC_RELAXED, __HIP_MEMORY_SCOPE_AGENT);
        union { uint32_t u; float f; } cv; cv.u = hv;
        ((uint16_t*)h_pk)[((1 - p) << 7) + j] = f32_to_f16u(cv.f);
      } else if (t >= 512 && t < 576){
        const int j = t - 512;
        uint32_t cw = __hip_atomic_load(&payc[((size_t)(Bp * SEQ + s)) * 64 + j],
                                        __ATOMIC_RELAXED, __HIP_MEMORY_SCOPE_AGENT);
        int chunk = 4 * (1 - p) + (j >> 4);
        c_pk[chunk][j & 15] = cw;
      }
      __syncthreads();                                 // B4
    }
  }
}

extern "C" void kernel_launch(void* const* d_in, const int* in_sizes, int n_in,
                              void* d_out, int out_size, void* d_ws, size_t ws_size,
                              hipStream_t stream){
  const int*   codes  = (const int*)  d_in[0];
  const float* mask   = (const float*)d_in[1];
  const float* times  = (const float*)d_in[2];
  const float* emb    = (const float*)d_in[3];
  const float* Wall_w = (const float*)d_in[4];
  const float* Wall_b = (const float*)d_in[5];
  const float* Uall_w = (const float*)d_in[6];
  const float* Uall_b = (const float*)d_in[7];
  const float* Wd_w   = (const float*)d_in[8];
  const float* Wd_b   = (const float*)d_in[9];
  float* out = (float*)d_out;

  char* ws = (char*)d_ws;
  const size_t offWpk   = 0;          // 524288
  const size_t offWdpk  = 524288;     // 131072
  const size_t offFlags = 655360;     // 262144
  const size_t offTs    = 917504;     // 131072
  const size_t offXp2   = 1048576;    // 67108864
  const size_t offPayc  = 68157440;   // 16777216  (x f16 staging aliased here)

  uint4*    wpk    = (uint4*)   (ws + offWpk);
  uint4*    wdpk   = (uint4*)   (ws + offWdpk);
  uint32_t* flags  = (uint32_t*)(ws + offFlags);
  float*    ts_all = (float*)   (ws + offTs);
  uint16_t* xp2    = (uint16_t*)(ws + offXp2);
  uint32_t* payc   = (uint32_t*)(ws + offPayc);
  uint16_t* xh     = (uint16_t*)(ws + offPayc);   // dead before recurrence

  hipMemsetAsync(ws + offFlags, 0, 262144, stream);
  hipLaunchKernelGGL(pack_wall, dim3(128), dim3(256), 0, stream, Wall_w, wpk);
  hipLaunchKernelGGL(pack_wd,   dim3(32),  dim3(256), 0, stream, Wd_w,   wdpk);
  hipLaunchKernelGGL(ts_k,      dim3(128), dim3(256), 0, stream, times, ts_all);
  hipLaunchKernelGGL(gather_x,  dim3(BATCH * SEQ), dim3(256), 0, stream, codes, mask, emb, xh);
  hipLaunchKernelGGL(xp_gemm,   dim3(16, 512), dim3(256), 0, stream, xh, Uall_w, Uall_b, xp2);
  hipLaunchKernelGGL(recurrence, dim3(256), dim3(1024), 0, stream,
                     wpk, wdpk, Wall_b, Wd_b, xp2, ts_all, flags, payc, out);
}

// Round 4
// 730.895 us; speedup vs baseline: 2.7524x; 2.7131x over previous
//
#include <hip/hip_runtime.h>
#include <stdint.h>

#define BATCH 128
#define SEQ   256
#define NC    16
#define HID   256
#define G4    1024

__device__ __forceinline__ uint16_t f32_to_f16u(float f){
  union { _Float16 h; uint16_t u; } c; c.h = (_Float16)f; return c.u;
}
__device__ __forceinline__ float f16u_to_f32(uint32_t u){
  union { uint16_t u; _Float16 h; } c; c.u = (uint16_t)u; return (float)c.h;
}
__device__ __forceinline__ float tanh_(float x){
  x = fminf(fmaxf(x, -15.f), 15.f);
  float e = __expf(2.f * x);
  return (e - 1.f) / (e + 1.f);
}
__device__ __forceinline__ float sigm_(float x){ return 1.f / (1.f + __expf(-x)); }

__device__ __forceinline__ int sdot4_(uint32_t a, uint32_t b, int c){
#if __has_builtin(__builtin_amdgcn_sdot4)
  return __builtin_amdgcn_sdot4((int)a, (int)b, c, false);
#else
  int ai = (int)a, bi = (int)b;
  c += ((ai << 24) >> 24) * ((bi << 24) >> 24);
  c += ((ai << 16) >> 24) * ((bi << 16) >> 24);
  c += ((ai <<  8) >> 24) * ((bi <<  8) >> 24);
  c += ( ai >> 24)        * ( bi >> 24);
  return c;
#endif
}
__device__ __forceinline__ uint32_t q4(const float* s, float sc){
  uint32_t r = 0;
  #pragma unroll
  for (int i = 0; i < 4; i++){
    int q = __float2int_rn(s[i] * sc);
    q = max(-127, min(127, q));
    r |= ((uint32_t)(q & 0xFF)) << (8 * i);
  }
  return r;
}

// Wall pack: wpk8[slot][t] uint4; slot = ri*8+jj (ri=gate 0..3, jj=0..7)
// t: rp=t>>1, kh=t&1; row = rp + ri*256; k in [kh*128 + jj*16, +16)
__global__ void pack_wall_i8(const float* __restrict__ W, uint4* __restrict__ out){
  int L = blockIdx.x * blockDim.x + threadIdx.x;
  if (L >= 32 * 512) return;
  int t = L & 511, slot = L >> 9;
  int ri = slot >> 3, jj = slot & 7;
  int rp = t >> 1, kh = t & 1;
  int row = rp + ri * 256;
  int kb = kh * 128 + jj * 16;
  const float* src = W + (size_t)row * 256 + kb;
  uint4 q;
  q.x = q4(src +  0, 2032.f);
  q.y = q4(src +  4, 2032.f);
  q.z = q4(src +  8, 2032.f);
  q.w = q4(src + 12, 2032.f);
  out[L] = q;
}
// Wd pack: wdpk8[jj][t]; unit = t>>1, kh = t&1; k in [kh*128 + jj*16, +16)
__global__ void pack_wd_i8(const float* __restrict__ W, uint4* __restrict__ out){
  int L = blockIdx.x * blockDim.x + threadIdx.x;
  if (L >= 8 * 512) return;
  int t = L & 511, jj = L >> 9;
  int unit = t >> 1, kh = t & 1;
  int kb = kh * 128 + jj * 16;
  const float* src = W + (size_t)unit * 256 + kb;
  uint4 q;
  q.x = q4(src +  0, 2032.f);
  q.y = q4(src +  4, 2032.f);
  q.z = q4(src +  8, 2032.f);
  q.w = q4(src + 12, 2032.f);
  out[L] = q;
}

__global__ void ts_k(const float* __restrict__ times, float* __restrict__ ts_all){
  int i = blockIdx.x * blockDim.x + threadIdx.x;
  if (i < BATCH * SEQ) ts_all[i] = 1.f / logf(times[i] + 2.7183f);
}

__global__ void gather_x(const int* __restrict__ codes, const float* __restrict__ mask,
                         const float* __restrict__ emb, uint16_t* __restrict__ xh){
  int bs = blockIdx.x;
  int t  = threadIdx.x;
  __shared__ int   scd[NC];
  __shared__ float smk[NC];
  if (t < NC){ scd[t] = codes[bs * NC + t]; smk[t] = mask[bs * NC + t]; }
  __syncthreads();
  float acc = 0.f;
  #pragma unroll
  for (int k = 0; k < NC; k++)
    acc += emb[(size_t)scd[k] * HID + t] * smk[k];
  xh[(size_t)bs * HID + t] = f32_to_f16u(acc);
}

// xp2[m][u*4 + gate] f16, m = b*SEQ+s, u = hidden unit, gate in {f,i,o,c}
__global__ __launch_bounds__(256) void xp_gemm(const uint16_t* __restrict__ xh,
    const float* __restrict__ Uw, const float* __restrict__ Ub,
    uint16_t* __restrict__ xp2){
  __shared__ float As[64][33];
  __shared__ float Bs[64][33];
  int tid = threadIdx.x;
  int m0 = blockIdx.y * 64, n0 = blockIdx.x * 64;
  int ty = tid >> 4, tx = tid & 15;
  int lr = tid >> 2, lc = (tid & 3) * 8;
  float acc[4][4] = {};
  for (int k0 = 0; k0 < 256; k0 += 32){
    uint4 av = *(const uint4*)(xh + (size_t)(m0 + lr) * 256 + k0 + lc);
    const float4* bp = (const float4*)(Uw + (size_t)(n0 + lr) * 256 + k0 + lc);
    float4 b0 = bp[0], b1 = bp[1];
    __syncthreads();
    As[lr][lc+0] = f16u_to_f32(av.x & 0xffff); As[lr][lc+1] = f16u_to_f32(av.x >> 16);
    As[lr][lc+2] = f16u_to_f32(av.y & 0xffff); As[lr][lc+3] = f16u_to_f32(av.y >> 16);
    As[lr][lc+4] = f16u_to_f32(av.z & 0xffff); As[lr][lc+5] = f16u_to_f32(av.z >> 16);
    As[lr][lc+6] = f16u_to_f32(av.w & 0xffff); As[lr][lc+7] = f16u_to_f32(av.w >> 16);
    Bs[lr][lc+0] = b0.x; Bs[lr][lc+1] = b0.y; Bs[lr][lc+2] = b0.z; Bs[lr][lc+3] = b0.w;
    Bs[lr][lc+4] = b1.x; Bs[lr][lc+5] = b1.y; Bs[lr][lc+6] = b1.z; Bs[lr][lc+7] = b1.w;
    __syncthreads();
    #pragma unroll
    for (int kk = 0; kk < 32; kk++){
      float a0 = As[ty*4+0][kk], a1 = As[ty*4+1][kk], a2 = As[ty*4+2][kk], a3 = As[ty*4+3][kk];
      float c0 = Bs[tx*4+0][kk], c1 = Bs[tx*4+1][kk], c2 = Bs[tx*4+2][kk], c3 = Bs[tx*4+3][kk];
      acc[0][0] += a0*c0; acc[0][1] += a0*c1; acc[0][2] += a0*c2; acc[0][3] += a0*c3;
      acc[1][0] += a1*c0; acc[1][1] += a1*c1; acc[1][2] += a1*c2; acc[1][3] += a1*c3;
      acc[2][0] += a2*c0; acc[2][1] += a2*c1; acc[2][2] += a2*c2; acc[2][3] += a2*c3;
      acc[3][0] += a3*c0; acc[3][1] += a3*c1; acc[3][2] += a3*c2; acc[3][3] += a3*c3;
    }
  }
  float bias[4];
  #pragma unroll
  for (int j = 0; j < 4; j++) bias[j] = Ub[n0 + tx*4 + j];
  #pragma unroll
  for (int i = 0; i < 4; i++){
    int m = m0 + ty*4 + i;
    #pragma unroll
    for (int j = 0; j < 4; j++){
      int rr = n0 + tx*4 + j;          // global gate-row [0,1024)
      int gate = rr >> 8, u = rr & 255;
      xp2[(size_t)m * 1024 + (u << 2) + gate] = f32_to_f16u(acc[i][j] + bias[j]);
    }
  }
}

// ---- recurrence: 128 blocks x 512 threads, all weights in registers (i8), no inter-block sync
__global__ __launch_bounds__(512) void recurrence(
    const uint4* __restrict__ wpk8, const uint4* __restrict__ wdpk8,
    const float* __restrict__ Wall_b, const float* __restrict__ Wd_b,
    const uint16_t* __restrict__ xp2, const float* __restrict__ ts_all,
    float* __restrict__ out)
{
  const int b = blockIdx.x;
  const int t = threadIdx.x;
  const int rp = t >> 1;          // hidden unit [0,256)
  const int kh = t & 1;           // k half
  const bool even = (kh == 0);

  __shared__ __align__(16) uint32_t h_ds[2][64];  // h as i8, scale 127
  __shared__ __align__(16) uint32_t c_ds[2][64];  // c as i8, scale 127/8

  // weights: 4 gate-rows (f,i,o,c of unit rp) x 128 k (half kh)
  uint4 ww[32];
  #pragma unroll
  for (int sl = 0; sl < 32; sl++) ww[sl] = wpk8[sl * 512 + t];
  uint4 wd8[8];
  #pragma unroll
  for (int jj = 0; jj < 8; jj++) wd8[jj] = wdpk8[jj * 512 + t];

  const float bF = Wall_b[rp];
  const float bI = Wall_b[rp + 256];
  const float bO = Wall_b[rp + 512];
  const float bC = Wall_b[rp + 768];
  const float bD = Wd_b[rp];
  const float SW  = 1.f / (2032.f * 127.f);     // Wall dequant
  const float SWD = 1.f / (2032.f * 15.875f);   // Wd dequant

  if (t < 128) ((uint32_t*)h_ds)[t];
  if (t < 128) ((uint32_t*)h_ds)[t] = 0u;
  else if (t < 256) ((uint32_t*)c_ds)[t - 128] = 0u;
  __syncthreads();

  const uint16_t* xp_b = xp2 + (size_t)b * SEQ * 1024;
  const float*    ts_b = ts_all + (size_t)b * SEQ;
  float* out_b = out + (size_t)b * SEQ * HID;

  float c_reg = 0.f;
  uint2 xv = make_uint2(0u, 0u);
  float tsv = 0.f;
  if (even){
    xv  = *(const uint2*)(xp_b + (rp << 2));
    tsv = ts_b[0];
  }

  for (int s = 0; s < SEQ; s++){
    const int buf = s & 1;
    // prefetch next step (even lanes)
    uint2 xn = make_uint2(0u, 0u);
    float tsn = 0.f;
    if (even && s + 1 < SEQ){
      xn  = *(const uint2*)(xp_b + (size_t)(s + 1) * 1024 + (rp << 2));
      tsn = ts_b[s + 1];
    }

    // Wall matvec: 4 gate rows over my k-half
    const uint4* hb = (const uint4*)&h_ds[buf][kh * 32];
    int a0 = 0, a1 = 0, a2 = 0, a3 = 0;
    #pragma unroll
    for (int jj = 0; jj < 8; jj++){
      uint4 hv = hb[jj];
      a0 = sdot4_(ww[jj].x, hv.x, a0);      a0 = sdot4_(ww[jj].y, hv.y, a0);
      a0 = sdot4_(ww[jj].z, hv.z, a0);      a0 = sdot4_(ww[jj].w, hv.w, a0);
      a1 = sdot4_(ww[8+jj].x, hv.x, a1);    a1 = sdot4_(ww[8+jj].y, hv.y, a1);
      a1 = sdot4_(ww[8+jj].z, hv.z, a1);    a1 = sdot4_(ww[8+jj].w, hv.w, a1);
      a2 = sdot4_(ww[16+jj].x, hv.x, a2);   a2 = sdot4_(ww[16+jj].y, hv.y, a2);
      a2 = sdot4_(ww[16+jj].z, hv.z, a2);   a2 = sdot4_(ww[16+jj].w, hv.w, a2);
      a3 = sdot4_(ww[24+jj].x, hv.x, a3);   a3 = sdot4_(ww[24+jj].y, hv.y, a3);
      a3 = sdot4_(ww[24+jj].z, hv.z, a3);   a3 = sdot4_(ww[24+jj].w, hv.w, a3);
    }
    // Wd matvec over my k-half
    const uint4* cb = (const uint4*)&c_ds[buf][kh * 32];
    int ad = 0;
    #pragma unroll
    for (int jj = 0; jj < 8; jj++){
      uint4 cv = cb[jj];
      ad = sdot4_(wd8[jj].x, cv.x, ad);  ad = sdot4_(wd8[jj].y, cv.y, ad);
      ad = sdot4_(wd8[jj].z, cv.z, ad);  ad = sdot4_(wd8[jj].w, cv.w, ad);
    }
    // pair reduce (k halves)
    a0 += __shfl_xor(a0, 1);
    a1 += __shfl_xor(a1, 1);
    a2 += __shfl_xor(a2, 1);
    a3 += __shfl_xor(a3, 1);
    ad += __shfl_xor(ad, 1);

    if (even){
      float pf = (float)a0 * SW + bF + f16u_to_f32(xv.x & 0xffff);
      float pi = (float)a1 * SW + bI + f16u_to_f32(xv.x >> 16);
      float po = (float)a2 * SW + bO + f16u_to_f32(xv.y & 0xffff);
      float pc = (float)a3 * SW + bC + f16u_to_f32(xv.y >> 16);
      float wdot = (float)ad * SWD + bD;
      float cs1  = tanh_(wdot);
      float cadj = (c_reg - cs1) + cs1 * tsv;
      float fg = sigm_(pf), ig = sigm_(pi), og = sigm_(po), ct = sigm_(pc);
      float cn = fg * cadj + ig * ct;
      float hn = og * tanh_(cn);
      c_reg = cn;
      out_b[(size_t)s * HID + rp] = hn;
      int hq = __float2int_rn(hn * 127.f);
      hq = max(-127, min(127, hq));
      float cc = fminf(fmaxf(cn, -7.9f), 7.9f);
      int cq = __float2int_rn(cc * 15.875f);
      ((int8_t*)&h_ds[buf ^ 1][0])[rp] = (int8_t)hq;
      ((int8_t*)&c_ds[buf ^ 1][0])[rp] = (int8_t)cq;
      xv = xn; tsv = tsn;
    }
    __syncthreads();
  }
}

extern "C" void kernel_launch(void* const* d_in, const int* in_sizes, int n_in,
                              void* d_out, int out_size, void* d_ws, size_t ws_size,
                              hipStream_t stream){
  const int*   codes  = (const int*)  d_in[0];
  const float* mask   = (const float*)d_in[1];
  const float* times  = (const float*)d_in[2];
  const float* emb    = (const float*)d_in[3];
  const float* Wall_w = (const float*)d_in[4];
  const float* Wall_b = (const float*)d_in[5];
  const float* Uall_w = (const float*)d_in[6];
  const float* Uall_b = (const float*)d_in[7];
  const float* Wd_w   = (const float*)d_in[8];
  const float* Wd_b   = (const float*)d_in[9];
  float* out = (float*)d_out;

  char* ws = (char*)d_ws;
  const size_t offWpk   = 0;          // 262144
  const size_t offWdpk  = 262144;     // 65536
  const size_t offTs    = 327680;     // 131072
  const size_t offXp2   = 458752;     // 67108864
  const size_t offXh    = 67567616;   // 16777216 -> ends 84344832

  uint4*    wpk8   = (uint4*)   (ws + offWpk);
  uint4*    wdpk8  = (uint4*)   (ws + offWdpk);
  float*    ts_all = (float*)   (ws + offTs);
  uint16_t* xp2    = (uint16_t*)(ws + offXp2);
  uint16_t* xh     = (uint16_t*)(ws + offXh);

  hipLaunchKernelGGL(pack_wall_i8, dim3(32), dim3(512), 0, stream, Wall_w, wpk8);
  hipLaunchKernelGGL(pack_wd_i8,   dim3(8),  dim3(512), 0, stream, Wd_w,   wdpk8);
  hipLaunchKernelGGL(ts_k,         dim3(128), dim3(256), 0, stream, times, ts_all);
  hipLaunchKernelGGL(gather_x,     dim3(BATCH * SEQ), dim3(256), 0, stream, codes, mask, emb, xh);
  hipLaunchKernelGGL(xp_gemm,      dim3(16, 512), dim3(256), 0, stream, xh, Uall_w, Uall_b, xp2);
  hipLaunchKernelGGL(recurrence,   dim3(BATCH), dim3(512), 0, stream,
                     wpk8, wdpk8, Wall_b, Wd_b, xp2, ts_all, out);
}

// Round 5
// 488.741 us; speedup vs baseline: 4.1162x; 1.4955x over previous
//
#include <hip/hip_runtime.h>
#include <stdint.h>

#define BATCH 128
#define SEQ   256
#define NC    16
#define HID   256
#define G4    1024

typedef _Float16 half8 __attribute__((ext_vector_type(8)));
typedef float    f32x4 __attribute__((ext_vector_type(4)));

__device__ __forceinline__ uint16_t f32_to_f16u(float f){
  union { _Float16 h; uint16_t u; } c; c.h = (_Float16)f; return c.u;
}
__device__ __forceinline__ float f16u_to_f32(uint32_t u){
  union { uint16_t u; _Float16 h; } c; c.u = (uint16_t)u; return (float)c.h;
}
__device__ __forceinline__ float tanh_(float x){
  x = fminf(fmaxf(x, -15.f), 15.f);
  float e = __expf(2.f * x);
  return (e - 1.f) / (e + 1.f);
}
__device__ __forceinline__ float sigm_(float x){ return 1.f / (1.f + __expf(-x)); }

__device__ __forceinline__ int sdot4_(uint32_t a, uint32_t b, int c){
#if __has_builtin(__builtin_amdgcn_sdot4)
  return __builtin_amdgcn_sdot4((int)a, (int)b, c, false);
#else
  int ai = (int)a, bi = (int)b;
  c += ((ai << 24) >> 24) * ((bi << 24) >> 24);
  c += ((ai << 16) >> 24) * ((bi << 16) >> 24);
  c += ((ai <<  8) >> 24) * ((bi <<  8) >> 24);
  c += ( ai >> 24)        * ( bi >> 24);
  return c;
#endif
}
__device__ __forceinline__ uint32_t q4(const float* s, float sc){
  uint32_t r = 0;
  #pragma unroll
  for (int i = 0; i < 4; i++){
    int q = __float2int_rn(s[i] * sc);
    q = max(-127, min(127, q));
    r |= ((uint32_t)(q & 0xFF)) << (8 * i);
  }
  return r;
}

// Wall pack: out[jj*1024 + t], t=(rp<<2)|g; row = g*256+rp; k in [jj*16, +16)
__global__ void pack_wall_i8(const float* __restrict__ W, uint4* __restrict__ out){
  int L = blockIdx.x * blockDim.x + threadIdx.x;
  if (L >= 16 * 1024) return;
  int t = L & 1023, jj = L >> 10;
  int rp = t >> 2, g = t & 3;
  int row = g * 256 + rp;
  const float* src = W + (size_t)row * 256 + jj * 16;
  uint4 q;
  q.x = q4(src +  0, 2032.f);
  q.y = q4(src +  4, 2032.f);
  q.z = q4(src +  8, 2032.f);
  q.w = q4(src + 12, 2032.f);
  out[L] = q;
}
// Wd pack: out[i4*1024 + t]; row = rp; k in [g*64 + i4*16, +16)
__global__ void pack_wd_i8(const float* __restrict__ W, uint4* __restrict__ out){
  int L = blockIdx.x * blockDim.x + threadIdx.x;
  if (L >= 4 * 1024) return;
  int t = L & 1023, i4 = L >> 10;
  int rp = t >> 2, g = t & 3;
  const float* src = W + (size_t)rp * 256 + g * 64 + i4 * 16;
  uint4 q;
  q.x = q4(src +  0, 2032.f);
  q.y = q4(src +  4, 2032.f);
  q.z = q4(src +  8, 2032.f);
  q.w = q4(src + 12, 2032.f);
  out[L] = q;
}

__global__ void pack_u16(const float* __restrict__ W, uint16_t* __restrict__ out, int n){
  int i = blockIdx.x * blockDim.x + threadIdx.x;
  if (i < n) out[i] = f32_to_f16u(W[i]);
}

__global__ void ts_k(const float* __restrict__ times, float* __restrict__ ts_all){
  int i = blockIdx.x * blockDim.x + threadIdx.x;
  if (i < BATCH * SEQ) ts_all[i] = 1.f / logf(times[i] + 2.7183f);
}

__global__ void gather_x(const int* __restrict__ codes, const float* __restrict__ mask,
                         const float* __restrict__ emb, uint16_t* __restrict__ xh){
  int bs = blockIdx.x;
  int t  = threadIdx.x;
  __shared__ int   scd[NC];
  __shared__ float smk[NC];
  if (t < NC){ scd[t] = codes[bs * NC + t]; smk[t] = mask[bs * NC + t]; }
  __syncthreads();
  float acc = 0.f;
  #pragma unroll
  for (int k = 0; k < NC; k++)
    acc += emb[(size_t)scd[k] * HID + t] * smk[k];
  xh[(size_t)bs * HID + t] = f32_to_f16u(acc);
}

// ---- xp GEMM via MFMA f16: C[m][n] = xh[m][k] * uh[n][k]; M=32768,N=1024,K=256
// output permuted: xp2[m][u*4+gate] f16, gate=n>>8, u=n&255
__global__ __launch_bounds__(256, 2) void xp_gemm_mfma(
    const uint16_t* __restrict__ xh, const uint16_t* __restrict__ uh,
    const float* __restrict__ Ub, uint16_t* __restrict__ xp2)
{
  __shared__ _Float16 As[128][40];   // +8 pad: de-conflict frag reads
  __shared__ _Float16 Bs[128][40];
  const int tid = threadIdx.x;
  const int m0 = blockIdx.y * 128, n0 = blockIdx.x * 128;
  const int w = tid >> 6, l = tid & 63;
  const int wr = w >> 1, wc = w & 1;
  const int sr0 = tid >> 2, sk0 = (tid & 3) * 8;

  f32x4 acc[4][4];
  #pragma unroll
  for (int i = 0; i < 4; i++)
    #pragma unroll
    for (int j = 0; j < 4; j++)
      acc[i][j] = (f32x4){0.f, 0.f, 0.f, 0.f};

  for (int k0 = 0; k0 < 256; k0 += 32){
    uint4 a0 = *(const uint4*)(xh + (size_t)(m0 + sr0) * 256 + k0 + sk0);
    uint4 a1 = *(const uint4*)(xh + (size_t)(m0 + 64 + sr0) * 256 + k0 + sk0);
    uint4 b0 = *(const uint4*)(uh + (size_t)(n0 + sr0) * 256 + k0 + sk0);
    uint4 b1 = *(const uint4*)(uh + (size_t)(n0 + 64 + sr0) * 256 + k0 + sk0);
    __syncthreads();
    *(uint4*)&As[sr0][sk0]      = a0;
    *(uint4*)&As[64 + sr0][sk0] = a1;
    *(uint4*)&Bs[sr0][sk0]      = b0;
    *(uint4*)&Bs[64 + sr0][sk0] = b1;
    __syncthreads();
    half8 af[4], bf[4];
    #pragma unroll
    for (int i = 0; i < 4; i++)
      af[i] = *(half8*)&As[wr*64 + i*16 + (l & 15)][(l >> 4) * 8];
    #pragma unroll
    for (int j = 0; j < 4; j++)
      bf[j] = *(half8*)&Bs[wc*64 + j*16 + (l & 15)][(l >> 4) * 8];
    #pragma unroll
    for (int i = 0; i < 4; i++)
      #pragma unroll
      for (int j = 0; j < 4; j++)
        acc[i][j] = __builtin_amdgcn_mfma_f32_16x16x32_f16(af[i], bf[j], acc[i][j], 0, 0, 0);
  }

  const int gate = n0 >> 8;
  #pragma unroll
  for (int j = 0; j < 4; j++){
    int ncol = wc*64 + j*16 + (l & 15);
    float bs = Ub[n0 + ncol];
    int u = (n0 & 255) + ncol;
    #pragma unroll
    for (int i = 0; i < 4; i++){
      #pragma unroll
      for (int r = 0; r < 4; r++){
        int m_e = m0 + wr*64 + i*16 + (l >> 4)*4 + r;
        xp2[(size_t)m_e * 1024 + u*4 + gate] = f32_to_f16u(acc[i][j][r] + bs);
      }
    }
  }
}

// ---- recurrence: 128 blocks x 1024 threads (16 waves = 4/SIMD)
// thread (rp=t>>2, g=t&3): Wall row g*256+rp full K (64 VGPR) + Wd row rp k-slice g (16 VGPR)
__global__ __launch_bounds__(1024, 4) void recurrence(
    const uint4* __restrict__ wpk8,   // [16][1024]
    const uint4* __restrict__ wdpk8,  // [4][1024]
    const float* __restrict__ Wall_b, const float* __restrict__ Wd_b,
    const uint16_t* __restrict__ xp2, const float* __restrict__ ts_all,
    float* __restrict__ out)
{
  const int b = blockIdx.x, t = threadIdx.x;
  const int rp = t >> 2, g = t & 3;

  __shared__ __align__(16) uint32_t h8[2][64];  // h[256] i8, scale 127
  __shared__ __align__(16) uint32_t c8[2][64];  // c[256] i8, scale 15.875

  uint4 ww[16];
  #pragma unroll
  for (int jj = 0; jj < 16; jj++) ww[jj] = wpk8[jj * 1024 + t];
  uint4 wd[4];
  #pragma unroll
  for (int i4 = 0; i4 < 4; i4++) wd[i4] = wdpk8[i4 * 1024 + t];

  const float biasW = Wall_b[g * 256 + rp];
  const float bD    = Wd_b[rp];
  const float SW  = 1.f / (2032.f * 127.f);
  const float SWD = 1.f / (2032.f * 15.875f);

  if (t < 128) ((uint32_t*)h8)[t] = 0u;
  else if (t < 256) ((uint32_t*)c8)[t - 128] = 0u;
  __syncthreads();

  const uint16_t* xp_b = xp2 + (size_t)b * SEQ * 1024;
  const float*    ts_b = ts_all + (size_t)b * SEQ;
  float* out_b = out + (size_t)b * SEQ * HID;

  float c_reg = 0.f;
  uint32_t xv = xp_b[t];
  float tsv = ts_b[0];

  for (int s = 0; s < SEQ; s++){
    const int buf = s & 1;
    uint32_t xn = 0; float tsn = 0.f;
    if (s + 1 < SEQ){
      xn  = xp_b[(size_t)(s + 1) * 1024 + t];
      tsn = ts_b[s + 1];
    }

    // Wall dot: full K=256, two chains for ILP; h reads are wave-broadcast
    const uint4* hb = (const uint4*)&h8[buf][0];
    int acc0 = 0, acc1 = 0;
    #pragma unroll
    for (int jj = 0; jj < 16; jj += 2){
      uint4 h0 = hb[jj];
      uint4 h1 = hb[jj + 1];
      acc0 = sdot4_(ww[jj].x,   h0.x, acc0);
      acc0 = sdot4_(ww[jj].y,   h0.y, acc0);
      acc0 = sdot4_(ww[jj].z,   h0.z, acc0);
      acc0 = sdot4_(ww[jj].w,   h0.w, acc0);
      acc1 = sdot4_(ww[jj+1].x, h1.x, acc1);
      acc1 = sdot4_(ww[jj+1].y, h1.y, acc1);
      acc1 = sdot4_(ww[jj+1].z, h1.z, acc1);
      acc1 = sdot4_(ww[jj+1].w, h1.w, acc1);
    }
    const int acc = acc0 + acc1;

    // Wd dot: k-slice g, reduce over 4-lane group
    const uint4* cbp = (const uint4*)&c8[buf][0];
    int ad = 0;
    #pragma unroll
    for (int i4 = 0; i4 < 4; i4++){
      uint4 cv = cbp[g * 4 + i4];
      ad = sdot4_(wd[i4].x, cv.x, ad);
      ad = sdot4_(wd[i4].y, cv.y, ad);
      ad = sdot4_(wd[i4].z, cv.z, ad);
      ad = sdot4_(wd[i4].w, cv.w, ad);
    }
    ad += __shfl_xor(ad, 1);
    ad += __shfl_xor(ad, 2);

    // per-gate activation locally (no redundant transcendentals)
    float pre = (float)acc * SW + biasW + f16u_to_f32(xv);
    float act = sigm_(pre);
    float a1v = __shfl_xor(act, 1);   // at g0: gate i
    float a2v = __shfl_xor(act, 2);   // at g0: gate o
    float a3v = __shfl_xor(act, 3);   // at g0: gate c_tmp

    if (g == 0){
      float wdot = (float)ad * SWD + bD;
      float cs1  = tanh_(wdot);
      float cadj = (c_reg - cs1) + cs1 * tsv;
      float cn = act * cadj + a1v * a3v;
      float hn = a2v * tanh_(cn);
      c_reg = cn;
      out_b[(size_t)s * HID + rp] = hn;
      int hq = __float2int_rn(hn * 127.f);
      hq = max(-127, min(127, hq));
      float cc = fminf(fmaxf(cn, -7.9f), 7.9f);
      int cq = __float2int_rn(cc * 15.875f);
      ((int8_t*)&h8[buf ^ 1][0])[rp] = (int8_t)hq;
      ((int8_t*)&c8[buf ^ 1][0])[rp] = (int8_t)cq;
    }
    xv = xn; tsv = tsn;
    __syncthreads();
  }
}

extern "C" void kernel_launch(void* const* d_in, const int* in_sizes, int n_in,
                              void* d_out, int out_size, void* d_ws, size_t ws_size,
                              hipStream_t stream){
  const int*   codes  = (const int*)  d_in[0];
  const float* mask   = (const float*)d_in[1];
  const float* times  = (const float*)d_in[2];
  const float* emb    = (const float*)d_in[3];
  const float* Wall_w = (const float*)d_in[4];
  const float* Wall_b = (const float*)d_in[5];
  const float* Uall_w = (const float*)d_in[6];
  const float* Uall_b = (const float*)d_in[7];
  const float* Wd_w   = (const float*)d_in[8];
  const float* Wd_b   = (const float*)d_in[9];
  float* out = (float*)d_out;

  char* ws = (char*)d_ws;
  const size_t offWpk  = 0;          // 262144
  const size_t offWdpk = 262144;     // 65536   -> 327680
  const size_t offTs   = 327680;     // 131072  -> 458752
  const size_t offUh   = 458752;     // 524288  -> 983040
  const size_t offXp2  = 983040;     // 67108864-> 68091904
  const size_t offXh   = 68091904;   // 16777216-> 84869120

  uint4*    wpk8   = (uint4*)   (ws + offWpk);
  uint4*    wdpk8  = (uint4*)   (ws + offWdpk);
  float*    ts_all = (float*)   (ws + offTs);
  uint16_t* uh     = (uint16_t*)(ws + offUh);
  uint16_t* xp2    = (uint16_t*)(ws + offXp2);
  uint16_t* xh     = (uint16_t*)(ws + offXh);

  hipLaunchKernelGGL(pack_wall_i8, dim3(64), dim3(256), 0, stream, Wall_w, wpk8);
  hipLaunchKernelGGL(pack_wd_i8,   dim3(16), dim3(256), 0, stream, Wd_w,   wdpk8);
  hipLaunchKernelGGL(pack_u16,     dim3(1024), dim3(256), 0, stream, Uall_w, uh, 1024 * 256);
  hipLaunchKernelGGL(ts_k,         dim3(128), dim3(256), 0, stream, times, ts_all);
  hipLaunchKernelGGL(gather_x,     dim3(BATCH * SEQ), dim3(256), 0, stream, codes, mask, emb, xh);
  hipLaunchKernelGGL(xp_gemm_mfma, dim3(8, 256), dim3(256), 0, stream, xh, uh, Uall_b, xp2);
  hipLaunchKernelGGL(recurrence,   dim3(BATCH), dim3(1024), 0, stream,
                     wpk8, wdpk8, Wall_b, Wd_b, xp2, ts_all, out);
}

// Round 6
// 485.272 us; speedup vs baseline: 4.1456x; 1.0071x over previous
//
#include <hip/hip_runtime.h>
#include <stdint.h>

#define BATCH 128
#define SEQ   256
#define NC    16
#define HID   256
#define G4    1024

typedef _Float16 half8 __attribute__((ext_vector_type(8)));
typedef float    f32x4 __attribute__((ext_vector_type(4)));
typedef int      i32x4 __attribute__((ext_vector_type(4)));

__device__ __forceinline__ uint16_t f32_to_f16u(float f){
  union { _Float16 h; uint16_t u; } c; c.h = (_Float16)f; return c.u;
}
__device__ __forceinline__ float f16u_to_f32(uint32_t u){
  union { uint16_t u; _Float16 h; } c; c.u = (uint16_t)u; return (float)c.h;
}
__device__ __forceinline__ float tanh_(float x){
  x = fminf(fmaxf(x, -15.f), 15.f);
  float e = __expf(2.f * x);
  return (e - 1.f) / (e + 1.f);
}
__device__ __forceinline__ float sigm_(float x){ return 1.f / (1.f + __expf(-x)); }

__device__ __forceinline__ uint32_t q4(const float* s, float sc){
  uint32_t r = 0;
  #pragma unroll
  for (int i = 0; i < 4; i++){
    int q = __float2int_rn(s[i] * sc);
    q = max(-127, min(127, q));
    r |= ((uint32_t)(q & 0xFF)) << (8 * i);
  }
  return r;
}

// ---- Wall pack as MFMA B-fragments ----
// recurrence reads ww[t][q] = wpkB[(t*4+q)*1024 + tid]; tid = w*64+l, c=l&15, r=l>>4
// B[k = q*64 + r*16 + j][col=c] = Wall[t*256 + w*16 + c][q*64 + r*16 + j]
__global__ void pack_wallB(const float* __restrict__ W, uint4* __restrict__ out){
  int L = blockIdx.x * blockDim.x + threadIdx.x;
  if (L >= 16 * 1024) return;
  int slot = L >> 10, tid = L & 1023;
  int t = slot >> 2, q = slot & 3;
  int w = tid >> 6, l = tid & 63;
  int c = l & 15, r = l >> 4;
  int row = t * 256 + w * 16 + c;
  int kb = q * 64 + r * 16;
  const float* src = W + (size_t)row * 256 + kb;
  uint4 v;
  v.x = q4(src +  0, 2032.f);
  v.y = q4(src +  4, 2032.f);
  v.z = q4(src +  8, 2032.f);
  v.w = q4(src + 12, 2032.f);
  out[L] = v;
}
// ---- Wd pack as MFMA B-fragments: wdB[q*1024 + tid]; row = w*16+c
__global__ void pack_wdB(const float* __restrict__ W, uint4* __restrict__ out){
  int L = blockIdx.x * blockDim.x + threadIdx.x;
  if (L >= 4 * 1024) return;
  int q = L >> 10, tid = L & 1023;
  int w = tid >> 6, l = tid & 63;
  int c = l & 15, r = l >> 4;
  int row = w * 16 + c;
  int kb = q * 64 + r * 16;
  const float* src = W + (size_t)row * 256 + kb;
  uint4 v;
  v.x = q4(src +  0, 2032.f);
  v.y = q4(src +  4, 2032.f);
  v.z = q4(src +  8, 2032.f);
  v.w = q4(src + 12, 2032.f);
  out[L] = v;
}

__global__ void pack_u16(const float* __restrict__ W, uint16_t* __restrict__ out, int n){
  int i = blockIdx.x * blockDim.x + threadIdx.x;
  if (i < n) out[i] = f32_to_f16u(W[i]);
}

__global__ void ts_k(const float* __restrict__ times, float* __restrict__ ts_all){
  int i = blockIdx.x * blockDim.x + threadIdx.x;
  if (i < BATCH * SEQ) ts_all[i] = 1.f / logf(times[i] + 2.7183f);
}

__global__ void gather_x(const int* __restrict__ codes, const float* __restrict__ mask,
                         const float* __restrict__ emb, uint16_t* __restrict__ xh){
  int bs = blockIdx.x;
  int t  = threadIdx.x;
  __shared__ int   scd[NC];
  __shared__ float smk[NC];
  if (t < NC){ scd[t] = codes[bs * NC + t]; smk[t] = mask[bs * NC + t]; }
  __syncthreads();
  float acc = 0.f;
  #pragma unroll
  for (int k = 0; k < NC; k++)
    acc += emb[(size_t)scd[k] * HID + t] * smk[k];
  xh[(size_t)bs * HID + t] = f32_to_f16u(acc);
}

// ---- xp GEMM via MFMA f16: C[m][n] = xh[m][k] * uh[n][k]; M=32768,N=1024,K=256
// output permuted: xp2[m][u*4+gate] f16, gate=n>>8, u=n&255
__global__ __launch_bounds__(256, 2) void xp_gemm_mfma(
    const uint16_t* __restrict__ xh, const uint16_t* __restrict__ uh,
    const float* __restrict__ Ub, uint16_t* __restrict__ xp2)
{
  __shared__ _Float16 As[128][40];
  __shared__ _Float16 Bs[128][40];
  const int tid = threadIdx.x;
  const int m0 = blockIdx.y * 128, n0 = blockIdx.x * 128;
  const int w = tid >> 6, l = tid & 63;
  const int wr = w >> 1, wc = w & 1;
  const int sr0 = tid >> 2, sk0 = (tid & 3) * 8;

  f32x4 acc[4][4];
  #pragma unroll
  for (int i = 0; i < 4; i++)
    #pragma unroll
    for (int j = 0; j < 4; j++)
      acc[i][j] = (f32x4){0.f, 0.f, 0.f, 0.f};

  for (int k0 = 0; k0 < 256; k0 += 32){
    uint4 a0 = *(const uint4*)(xh + (size_t)(m0 + sr0) * 256 + k0 + sk0);
    uint4 a1 = *(const uint4*)(xh + (size_t)(m0 + 64 + sr0) * 256 + k0 + sk0);
    uint4 b0 = *(const uint4*)(uh + (size_t)(n0 + sr0) * 256 + k0 + sk0);
    uint4 b1 = *(const uint4*)(uh + (size_t)(n0 + 64 + sr0) * 256 + k0 + sk0);
    __syncthreads();
    *(uint4*)&As[sr0][sk0]      = a0;
    *(uint4*)&As[64 + sr0][sk0] = a1;
    *(uint4*)&Bs[sr0][sk0]      = b0;
    *(uint4*)&Bs[64 + sr0][sk0] = b1;
    __syncthreads();
    half8 af[4], bf[4];
    #pragma unroll
    for (int i = 0; i < 4; i++)
      af[i] = *(half8*)&As[wr*64 + i*16 + (l & 15)][(l >> 4) * 8];
    #pragma unroll
    for (int j = 0; j < 4; j++)
      bf[j] = *(half8*)&Bs[wc*64 + j*16 + (l & 15)][(l >> 4) * 8];
    #pragma unroll
    for (int i = 0; i < 4; i++)
      #pragma unroll
      for (int j = 0; j < 4; j++)
        acc[i][j] = __builtin_amdgcn_mfma_f32_16x16x32_f16(af[i], bf[j], acc[i][j], 0, 0, 0);
  }

  const int gate = n0 >> 8;
  #pragma unroll
  for (int j = 0; j < 4; j++){
    int ncol = wc*64 + j*16 + (l & 15);
    float bs = Ub[n0 + ncol];
    int u = (n0 & 255) + ncol;
    #pragma unroll
    for (int i = 0; i < 4; i++){
      #pragma unroll
      for (int r = 0; r < 4; r++){
        int m_e = m0 + wr*64 + i*16 + (l >> 4)*4 + r;
        xp2[(size_t)m_e * 1024 + u*4 + gate] = f32_to_f16u(acc[i][j][r] + bs);
      }
    }
  }
}

// ---- recurrence: 128 blocks x 1024 threads (16 waves = 4/SIMD)
// wave w, lane l: c=l&15, r=l>>4 (4-way replica). Unit U = w*16+c.
// Wall via mfma_i32_16x16x64_i8: A = h (i8) replicated across rows, B = weight frags.
// Tile t = gate t -> each lane's acc[t] holds gate t of its unit. No gate shuffles.
__global__ __launch_bounds__(1024, 4) void recurrence(
    const i32x4* __restrict__ wpkB,   // [16][1024]
    const i32x4* __restrict__ wdB,    // [4][1024]
    const float* __restrict__ Wall_b, const float* __restrict__ Wd_b,
    const uint16_t* __restrict__ xp2, const float* __restrict__ ts_all,
    float* __restrict__ out)
{
  const int b = blockIdx.x, tid = threadIdx.x;
  const int l = tid & 63;
  const int c = l & 15, r = l >> 4;
  const int U = (tid >> 6) * 16 + c;     // unit this lane owns

  __shared__ __align__(16) uint32_t h8[2][64];  // h[256] i8, scale 127
  __shared__ __align__(16) uint32_t c8[2][64];  // c[256] i8, scale 15.875

  i32x4 ww[4][4];
  #pragma unroll
  for (int t = 0; t < 4; t++)
    #pragma unroll
    for (int q = 0; q < 4; q++)
      ww[t][q] = wpkB[(t * 4 + q) * 1024 + tid];
  i32x4 wd[4];
  #pragma unroll
  for (int q = 0; q < 4; q++) wd[q] = wdB[q * 1024 + tid];

  const float bWf = Wall_b[U];
  const float bWi = Wall_b[U + 256];
  const float bWo = Wall_b[U + 512];
  const float bWc = Wall_b[U + 768];
  const float bD  = Wd_b[U];
  const float SW  = 1.f / (2032.f * 127.f);
  const float SWD = 1.f / (2032.f * 15.875f);

  if (tid < 128) ((uint32_t*)h8)[tid] = 0u;
  else if (tid < 256) ((uint32_t*)c8)[tid - 128] = 0u;
  __syncthreads();

  const uint16_t* xp_b = xp2 + (size_t)b * SEQ * 1024;
  const float*    ts_b = ts_all + (size_t)b * SEQ;
  float* out_b = out + (size_t)b * SEQ * HID;

  float c_reg = 0.f;
  float hn_prev = 0.f;
  uint2 xv = *(const uint2*)(xp_b + (U << 2));
  float tsv = ts_b[0];

  for (int s = 0; s < SEQ; s++){
    const int buf = s & 1;

    // delayed store of previous step's h (drain hides under this step)
    if (s > 0 && r == 0) out_b[(size_t)(s - 1) * HID + U] = hn_prev;

    // prefetch next step
    uint2 xn = make_uint2(0u, 0u); float tsn = 0.f;
    if (s + 1 < SEQ){
      xn  = *(const uint2*)(xp_b + (size_t)(s + 1) * 1024 + (U << 2));
      tsn = ts_b[s + 1];
    }

    // A-fragments: h and c replicated (addr uniform per 16-lane group, conflict-free)
    const char* hbase = (const char*)&h8[buf][0];
    const char* cbase = (const char*)&c8[buf][0];
    i32x4 hA[4], cA[4];
    #pragma unroll
    for (int q = 0; q < 4; q++){
      hA[q] = *(const i32x4*)(hbase + q * 64 + r * 16);
      cA[q] = *(const i32x4*)(cbase + q * 64 + r * 16);
    }

    // Wd matvec on MFMA pipe
    i32x4 ad = (i32x4){0, 0, 0, 0};
    #pragma unroll
    for (int q = 0; q < 4; q++)
      ad = __builtin_amdgcn_mfma_i32_16x16x64_i8(cA[q], wd[q], ad, 0, 0, 0);

    // Wall matvec: 4 gate tiles
    i32x4 a0 = (i32x4){0,0,0,0}, a1 = (i32x4){0,0,0,0}, a2 = (i32x4){0,0,0,0}, a3 = (i32x4){0,0,0,0};
    #pragma unroll
    for (int q = 0; q < 4; q++) a0 = __builtin_amdgcn_mfma_i32_16x16x64_i8(hA[q], ww[0][q], a0, 0, 0, 0);
    #pragma unroll
    for (int q = 0; q < 4; q++) a1 = __builtin_amdgcn_mfma_i32_16x16x64_i8(hA[q], ww[1][q], a1, 0, 0, 0);
    #pragma unroll
    for (int q = 0; q < 4; q++) a2 = __builtin_amdgcn_mfma_i32_16x16x64_i8(hA[q], ww[2][q], a2, 0, 0, 0);
    #pragma unroll
    for (int q = 0; q < 4; q++) a3 = __builtin_amdgcn_mfma_i32_16x16x64_i8(hA[q], ww[3][q], a3, 0, 0, 0);

    // gate math (all lanes; replicas redundant but uniform)
    float pf = (float)a0[0] * SW + bWf + f16u_to_f32(xv.x & 0xffff);
    float pi = (float)a1[0] * SW + bWi + f16u_to_f32(xv.x >> 16);
    float po = (float)a2[0] * SW + bWo + f16u_to_f32(xv.y & 0xffff);
    float pc = (float)a3[0] * SW + bWc + f16u_to_f32(xv.y >> 16);
    float wdot = (float)ad[0] * SWD + bD;

    float fg = sigm_(pf), ig = sigm_(pi), og = sigm_(po), ct = sigm_(pc);
    float cs1  = tanh_(wdot);
    float cadj = (c_reg - cs1) + cs1 * tsv;
    float cn = fg * cadj + ig * ct;
    float hn = og * tanh_(cn);
    c_reg = cn;
    hn_prev = hn;

    // quantize + publish next-step state (replica 0 only)
    if (r == 0){
      int hq = __float2int_rn(hn * 127.f);
      hq = max(-127, min(127, hq));
      float cc = fminf(fmaxf(cn, -7.9f), 7.9f);
      int cq = __float2int_rn(cc * 15.875f);
      ((int8_t*)&h8[buf ^ 1][0])[U] = (int8_t)hq;
      ((int8_t*)&c8[buf ^ 1][0])[U] = (int8_t)cq;
    }
    xv = xn; tsv = tsn;
    __syncthreads();
  }
  if (r == 0) out_b[(size_t)(SEQ - 1) * HID + U] = hn_prev;
}

extern "C" void kernel_launch(void* const* d_in, const int* in_sizes, int n_in,
                              void* d_out, int out_size, void* d_ws, size_t ws_size,
                              hipStream_t stream){
  const int*   codes  = (const int*)  d_in[0];
  const float* mask   = (const float*)d_in[1];
  const float* times  = (const float*)d_in[2];
  const float* emb    = (const float*)d_in[3];
  const float* Wall_w = (const float*)d_in[4];
  const float* Wall_b = (const float*)d_in[5];
  const float* Uall_w = (const float*)d_in[6];
  const float* Uall_b = (const float*)d_in[7];
  const float* Wd_w   = (const float*)d_in[8];
  const float* Wd_b   = (const float*)d_in[9];
  float* out = (float*)d_out;

  char* ws = (char*)d_ws;
  const size_t offWpk  = 0;          // 262144
  const size_t offWd   = 262144;     // 65536   -> 327680
  const size_t offTs   = 327680;     // 131072  -> 458752
  const size_t offUh   = 458752;     // 524288  -> 983040
  const size_t offXp2  = 983040;     // 67108864-> 68091904
  const size_t offXh   = 68091904;   // 16777216-> 84869120

  uint4*    wpkB   = (uint4*)   (ws + offWpk);
  uint4*    wdB    = (uint4*)   (ws + offWd);
  float*    ts_all = (float*)   (ws + offTs);
  uint16_t* uh     = (uint16_t*)(ws + offUh);
  uint16_t* xp2    = (uint16_t*)(ws + offXp2);
  uint16_t* xh     = (uint16_t*)(ws + offXh);

  hipLaunchKernelGGL(pack_wallB, dim3(64), dim3(256), 0, stream, Wall_w, wpkB);
  hipLaunchKernelGGL(pack_wdB,   dim3(16), dim3(256), 0, stream, Wd_w,   wdB);
  hipLaunchKernelGGL(pack_u16,   dim3(1024), dim3(256), 0, stream, Uall_w, uh, 1024 * 256);
  hipLaunchKernelGGL(ts_k,       dim3(128), dim3(256), 0, stream, times, ts_all);
  hipLaunchKernelGGL(gather_x,   dim3(BATCH * SEQ), dim3(256), 0, stream, codes, mask, emb, xh);
  hipLaunchKernelGGL(xp_gemm_mfma, dim3(8, 256), dim3(256), 0, stream, xh, uh, Uall_b, xp2);
  hipLaunchKernelGGL(recurrence, dim3(BATCH), dim3(1024), 0, stream,
                     (const i32x4*)wpkB, (const i32x4*)wdB, Wall_b, Wd_b, xp2, ts_all, out);
}